// Round 1
// baseline (1656.097 us; speedup 1.0000x reference)
//
#include <hip/hip_runtime.h>
#include <hip/hip_bf16.h>

// Problem constants (match reference)
#define NNODES 100000
#define NEDGES 3200000
#define INDIM  512
#define HID    128
#define NCLS   64

typedef __bf16 bf16x8 __attribute__((ext_vector_type(8)));
typedef __bf16 bf16x4 __attribute__((ext_vector_type(4)));
typedef float  f32x4  __attribute__((ext_vector_type(4)));

#define APAD 40    // k-pad for 32-wide k tiles (80B row stride: 16B-aligned, 2-way banks = free)
#define HPAD 136   // k-pad for 128-wide k (272B stride, 16B-aligned)

// ---------------------------------------------------------------------------
// Fused dense phase: h1 = relu(X @ W0) @ W1   (bf16 MFMA, fp32 accumulate)
// Block = 256 thr (4 waves), 64 rows/block, full 128-wide N for GEMM1.
// Each wave owns a 16-row stripe; GEMM2 done per-wave from LDS (no barrier).
// ---------------------------------------------------------------------------
__global__ __launch_bounds__(256, 2)
void gemm_fused(const float* __restrict__ feat, const float* __restrict__ W0,
                const float* __restrict__ W1, float* __restrict__ h1) {
  __shared__ __bf16 As[64 * APAD];      // X tile, row-major [64][40]
  __shared__ __bf16 Bs[HID * APAD];     // W0 tile transposed, [n=128][k pad 40]
  __shared__ __bf16 h0s[64 * HPAD];     // relu(X@W0) tile, A-operand layout
  __shared__ __bf16 W1s[NCLS * HPAD];   // W1 transposed, [n=64][k=128 pad 136]

  const int tid  = threadIdx.x;
  const int wave = tid >> 6;
  const int lane = tid & 63;
  const int q    = lane >> 4;
  const int l16  = lane & 15;
  const int rb   = blockIdx.x * 64;

  // Stage W1 [128][64] fp32 -> W1s[n][k] bf16 (once). 2048 float4 / 256 thr.
#pragma unroll
  for (int i = 0; i < 8; ++i) {
    int idx = tid + i * 256;
    int k   = idx >> 4;           // 16 float4 per k-row
    int n4  = (idx & 15) * 4;
    const float4 w = *(const float4*)&W1[k * NCLS + n4];
    W1s[(n4 + 0) * HPAD + k] = (__bf16)w.x;
    W1s[(n4 + 1) * HPAD + k] = (__bf16)w.y;
    W1s[(n4 + 2) * HPAD + k] = (__bf16)w.z;
    W1s[(n4 + 3) * HPAD + k] = (__bf16)w.w;
  }

  f32x4 acc[8];
#pragma unroll
  for (int t = 0; t < 8; ++t) acc[t] = (f32x4){0.f, 0.f, 0.f, 0.f};

  for (int kk = 0; kk < INDIM / 32; ++kk) {
    const int k0 = kk * 32;
    // Stage A: 64 rows x 32 k fp32 -> bf16.  512 float4, 2/thread.
#pragma unroll
    for (int i = 0; i < 2; ++i) {
      int idx = tid + i * 256;
      int r   = idx >> 3;
      int kf  = (idx & 7) * 4;
      int grow = rb + r;
      if (grow >= NNODES) grow = NNODES - 1;   // clamp; OOB rows never stored
      const float4 a = *(const float4*)&feat[(size_t)grow * INDIM + k0 + kf];
      bf16x4 v;
      v[0] = (__bf16)a.x; v[1] = (__bf16)a.y; v[2] = (__bf16)a.z; v[3] = (__bf16)a.w;
      *(bf16x4*)&As[r * APAD + kf] = v;
    }
    // Stage B: W0 rows k0..k0+31, all 128 n; transpose to [n][k]. 1024 float4, 4/thread.
#pragma unroll
    for (int i = 0; i < 4; ++i) {
      int idx = tid + i * 256;
      int kr  = idx >> 5;
      int nf  = (idx & 31) * 4;
      const float4 w = *(const float4*)&W0[(size_t)(k0 + kr) * HID + nf];
      Bs[(nf + 0) * APAD + kr] = (__bf16)w.x;
      Bs[(nf + 1) * APAD + kr] = (__bf16)w.y;
      Bs[(nf + 2) * APAD + kr] = (__bf16)w.z;
      Bs[(nf + 3) * APAD + kr] = (__bf16)w.w;
    }
    __syncthreads();
    // A-frag: A[m=lane&15][k=q*8+j] — 16B contiguous read
    const bf16x8 aF = *(const bf16x8*)&As[(wave * 16 + l16) * APAD + q * 8];
#pragma unroll
    for (int t = 0; t < 8; ++t) {
      const bf16x8 bF = *(const bf16x8*)&Bs[(t * 16 + l16) * APAD + q * 8];
      acc[t] = __builtin_amdgcn_mfma_f32_16x16x32_bf16(aF, bF, acc[t], 0, 0, 0);
    }
    __syncthreads();
  }

  // ReLU + cvt, deposit h0 into LDS in A-operand layout (C/D: row=q*4+j, col=l16)
#pragma unroll
  for (int t = 0; t < 8; ++t) {
#pragma unroll
    for (int j = 0; j < 4; ++j) {
      float v = acc[t][j];
      v = v > 0.f ? v : 0.f;
      h0s[(wave * 16 + q * 4 + j) * HPAD + t * 16 + l16] = (__bf16)v;
    }
  }
  // No __syncthreads needed: each wave reads only its own 16-row h0s stripe.

  f32x4 acc2[4];
#pragma unroll
  for (int t = 0; t < 4; ++t) acc2[t] = (f32x4){0.f, 0.f, 0.f, 0.f};
#pragma unroll
  for (int kk = 0; kk < HID / 32; ++kk) {
    const bf16x8 aF = *(const bf16x8*)&h0s[(wave * 16 + l16) * HPAD + kk * 32 + q * 8];
#pragma unroll
    for (int t = 0; t < 4; ++t) {
      const bf16x8 bF = *(const bf16x8*)&W1s[(t * 16 + l16) * HPAD + kk * 32 + q * 8];
      acc2[t] = __builtin_amdgcn_mfma_f32_16x16x32_bf16(aF, bF, acc2[t], 0, 0, 0);
    }
  }

#pragma unroll
  for (int t = 0; t < 4; ++t) {
#pragma unroll
    for (int j = 0; j < 4; ++j) {
      int grow = rb + wave * 16 + q * 4 + j;
      if (grow < NNODES) h1[(size_t)grow * NCLS + t * 16 + l16] = acc2[t][j];
    }
  }
}

// ---------------------------------------------------------------------------
// CSR-by-dst build: histogram -> 2-level exclusive scan -> atomic fill
// ---------------------------------------------------------------------------
#define SCAN_NB 98   // ceil(100000 / 1024)

__global__ void k_hist(const int* __restrict__ dst, int* __restrict__ deg) {
  int i = blockIdx.x * 256 + threadIdx.x;
  if (i < NEDGES) atomicAdd(&deg[dst[i]], 1);
}

__global__ void k_scan1(const int* __restrict__ deg, int* __restrict__ rowptr,
                        int* __restrict__ bsum) {
  __shared__ int s[256];
  const int t = threadIdx.x;
  const int base = blockIdx.x * 1024 + t * 4;
  int v0 = (base + 0 < NNODES) ? deg[base + 0] : 0;
  int v1 = (base + 1 < NNODES) ? deg[base + 1] : 0;
  int v2 = (base + 2 < NNODES) ? deg[base + 2] : 0;
  int v3 = (base + 3 < NNODES) ? deg[base + 3] : 0;
  const int tsum = v0 + v1 + v2 + v3;
  s[t] = tsum;
  __syncthreads();
  for (int off = 1; off < 256; off <<= 1) {
    int x = (t >= off) ? s[t - off] : 0;
    __syncthreads();
    s[t] += x;
    __syncthreads();
  }
  const int excl = s[t] - tsum;
  if (t == 255) bsum[blockIdx.x] = s[255];
  if (base + 0 < NNODES) rowptr[base + 0] = excl;
  if (base + 1 < NNODES) rowptr[base + 1] = excl + v0;
  if (base + 2 < NNODES) rowptr[base + 2] = excl + v0 + v1;
  if (base + 3 < NNODES) rowptr[base + 3] = excl + v0 + v1 + v2;
}

__global__ void k_scan2(const int* __restrict__ bsum, int* __restrict__ bofs,
                        int* __restrict__ rowptr) {
  __shared__ int s[128];
  const int t = threadIdx.x;
  const int v = (t < SCAN_NB) ? bsum[t] : 0;
  s[t] = v;
  __syncthreads();
  for (int off = 1; off < 128; off <<= 1) {
    int x = (t >= off) ? s[t - off] : 0;
    __syncthreads();
    s[t] += x;
    __syncthreads();
  }
  if (t < SCAN_NB) bofs[t] = s[t] - v;
  if (t == 127) rowptr[NNODES] = s[127];   // == NEDGES
}

__global__ void k_scan3(int* __restrict__ rowptr, const int* __restrict__ bofs,
                        int* __restrict__ nextpos) {
  const int i = blockIdx.x * 256 + threadIdx.x;
  if (i < NNODES) {
    const int r = rowptr[i] + bofs[i >> 10];
    rowptr[i] = r;
    nextpos[i] = r;
  }
}

__global__ void k_fill(const int* __restrict__ dst, int* __restrict__ nextpos,
                       int* __restrict__ perm) {
  int i = blockIdx.x * 256 + threadIdx.x;
  if (i < NEDGES) {
    const int p = atomicAdd(&nextpos[dst[i]], 1);
    perm[p] = i;
  }
}

// ---------------------------------------------------------------------------
// SpMM gather: one wave per dst row, lane = output column (NC=64 == wave)
// ---------------------------------------------------------------------------
__global__ __launch_bounds__(256, 4)
void k_spmm(const int* __restrict__ rowptr, const int* __restrict__ perm,
            const int* __restrict__ src, const float* __restrict__ val,
            const float* __restrict__ x, float* __restrict__ y) {
  const int w    = (blockIdx.x * 256 + threadIdx.x) >> 6;
  const int lane = threadIdx.x & 63;
  if (w >= NNODES) return;
  const int beg = rowptr[w];
  const int end = rowptr[w + 1];
  float acc = 0.f;
  for (int i = beg; i < end; ++i) {
    const int e = perm[i];                        // wave-uniform loads
    acc += val[e] * x[(size_t)src[e] * NCLS + lane];  // coalesced 256B row gather
  }
  y[(size_t)w * NCLS + lane] = acc;
}

// ---------------------------------------------------------------------------
extern "C" void kernel_launch(void* const* d_in, const int* in_sizes, int n_in,
                              void* d_out, int out_size, void* d_ws, size_t ws_size,
                              hipStream_t stream) {
  const float* feat = (const float*)d_in[0];
  const float* W0   = (const float*)d_in[1];
  const float* W1   = (const float*)d_in[2];
  const float* eval = (const float*)d_in[3];
  const int*   esrc = (const int*)d_in[4];
  const int*   edst = (const int*)d_in[5];
  float* out = (float*)d_out;

  // Workspace carve-up (all offsets 256B-aligned); total ~65.2 MB
  char* p = (char*)d_ws;
  float* h1      = (float*)p; p += 25600000;   // N*64*4
  float* h2      = (float*)p; p += 25600000;
  int*   deg     = (int*)p;   p += 400128;
  int*   rowptr  = (int*)p;   p += 400128;     // N+1 ints
  int*   nextpos = (int*)p;   p += 400128;
  int*   perm    = (int*)p;   p += 12800000;   // E ints
  int*   bsum    = (int*)p;   p += 512;
  int*   bofs    = (int*)p;   p += 512;

  hipMemsetAsync(deg, 0, NNODES * sizeof(int), stream);
  k_hist <<<NEDGES / 256, 256, 0, stream>>>(edst, deg);
  k_scan1<<<SCAN_NB, 256, 0, stream>>>(deg, rowptr, bsum);
  k_scan2<<<1, 128, 0, stream>>>(bsum, bofs, rowptr);
  k_scan3<<<(NNODES + 255) / 256, 256, 0, stream>>>(rowptr, bofs, nextpos);
  k_fill <<<NEDGES / 256, 256, 0, stream>>>(edst, nextpos, perm);

  gemm_fused<<<(NNODES + 63) / 64, 256, 0, stream>>>(feat, W0, W1, h1);

  k_spmm<<<NNODES / 4, 256, 0, stream>>>(rowptr, perm, esrc, eval, h1, h2);
  k_spmm<<<NNODES / 4, 256, 0, stream>>>(rowptr, perm, esrc, eval, h2, out);

  (void)in_sizes; (void)n_in; (void)out_size; (void)ws_size;
}

// Round 2
// 845.871 us; speedup vs baseline: 1.9579x; 1.9579x over previous
//
#include <hip/hip_runtime.h>
#include <hip/hip_bf16.h>

// Problem constants (match reference)
#define NNODES 100000
#define NEDGES 3200000
#define INDIM  512
#define HID    128
#define NCLS   64

typedef __bf16 bf16x8 __attribute__((ext_vector_type(8)));
typedef float  f32x4  __attribute__((ext_vector_type(4)));

#define APAD 40    // k-pad for 32-wide k tiles (80B row stride, 16B-aligned)
#define HPAD 136   // k-pad for 128-wide k (272B stride, 16B-aligned)

#define PADCAP (NEDGES + 3 * NNODES)   // max padded edge count (pad deg to x4)

// ---------------------------------------------------------------------------
// One-shot weight transpose + bf16 convert: W0T[n=128][k=512], W1T[n=64][k=128]
// ---------------------------------------------------------------------------
__global__ void k_wcvt(const float* __restrict__ W0, const float* __restrict__ W1,
                       __bf16* __restrict__ W0T, __bf16* __restrict__ W1T) {
  const int i = blockIdx.x * 256 + threadIdx.x;
  if (i < 65536) {              // W0 is [512][128]
    const int n = i >> 9, k = i & 511;
    W0T[i] = (__bf16)W0[k * HID + n];
  }
  if (i < 8192) {               // W1 is [128][64]
    const int n = i >> 7, k = i & 127;
    W1T[i] = (__bf16)W1[k * NCLS + n];
  }
}

// ---------------------------------------------------------------------------
// Fused dense phase: h1 = relu(X @ W0) @ W1   (bf16 MFMA, fp32 accumulate)
// 256 thr (4 waves), 64 rows/block. A-frags straight from global (coalesced
// 128B/row segments); Bs staged as plain 16B copies from pre-transposed W0T.
// ---------------------------------------------------------------------------
__global__ __launch_bounds__(256, 4)
void gemm_fused(const float* __restrict__ feat, const __bf16* __restrict__ W0T,
                const __bf16* __restrict__ W1T, float* __restrict__ h1) {
  __shared__ __bf16 Bs[HID * APAD];     // W0T k-tile [n=128][k=32 pad 40]
  __shared__ __bf16 h0s[64 * HPAD];     // relu(X@W0) tile, A-operand layout

  const int tid  = threadIdx.x;
  const int wave = tid >> 6;
  const int lane = tid & 63;
  const int q    = lane >> 4;
  const int l16  = lane & 15;
  const int rb   = blockIdx.x * 64;

  int row = rb + wave * 16 + l16;
  if (row >= NNODES) row = NNODES - 1;          // clamped loads; stores guarded
  const float* __restrict__ arow = feat + (size_t)row * INDIM;

  f32x4 acc[8];
#pragma unroll
  for (int t = 0; t < 8; ++t) acc[t] = (f32x4){0.f, 0.f, 0.f, 0.f};

  for (int kk = 0; kk < INDIM / 32; ++kk) {
    const int k0 = kk * 32;
    // Stage Bs: 512 x 16B chunks, 2 per thread, no transpose (W0T is [n][k]).
#pragma unroll
    for (int i = 0; i < 2; ++i) {
      const int c  = tid + i * 256;
      const int n  = c >> 2;
      const int ko = (c & 3) * 8;
      *(bf16x8*)&Bs[n * APAD + ko] = *(const bf16x8*)&W0T[n * INDIM + k0 + ko];
    }
    // A-frag from global: lanes {l16 + 16q} cover 128B contiguous per row.
    const float4 a0 = *(const float4*)&arow[k0 + q * 8];
    const float4 a1 = *(const float4*)&arow[k0 + q * 8 + 4];
    bf16x8 aF;
    aF[0] = (__bf16)a0.x; aF[1] = (__bf16)a0.y; aF[2] = (__bf16)a0.z; aF[3] = (__bf16)a0.w;
    aF[4] = (__bf16)a1.x; aF[5] = (__bf16)a1.y; aF[6] = (__bf16)a1.z; aF[7] = (__bf16)a1.w;
    __syncthreads();
#pragma unroll
    for (int t = 0; t < 8; ++t) {
      const bf16x8 bF = *(const bf16x8*)&Bs[(t * 16 + l16) * APAD + q * 8];
      acc[t] = __builtin_amdgcn_mfma_f32_16x16x32_bf16(aF, bF, acc[t], 0, 0, 0);
    }
    __syncthreads();
  }

  // ReLU + cvt -> h0s in A-operand layout (C/D: row=q*4+j, col=l16)
#pragma unroll
  for (int t = 0; t < 8; ++t) {
#pragma unroll
    for (int j = 0; j < 4; ++j) {
      float v = acc[t][j];
      v = v > 0.f ? v : 0.f;
      h0s[(wave * 16 + q * 4 + j) * HPAD + t * 16 + l16] = (__bf16)v;
    }
  }
  // No barrier: each wave reads only its own 16-row h0s stripe.

  f32x4 acc2[4];
#pragma unroll
  for (int t = 0; t < 4; ++t) acc2[t] = (f32x4){0.f, 0.f, 0.f, 0.f};
#pragma unroll
  for (int kk = 0; kk < HID / 32; ++kk) {
    const bf16x8 aF = *(const bf16x8*)&h0s[(wave * 16 + l16) * HPAD + kk * 32 + q * 8];
#pragma unroll
    for (int t = 0; t < 4; ++t) {
      const bf16x8 bF = *(const bf16x8*)&W1T[(t * 16 + l16) * HID + kk * 32 + q * 8];
      acc2[t] = __builtin_amdgcn_mfma_f32_16x16x32_bf16(aF, bF, acc2[t], 0, 0, 0);
    }
  }

#pragma unroll
  for (int t = 0; t < 4; ++t) {
#pragma unroll
    for (int j = 0; j < 4; ++j) {
      const int grow = rb + wave * 16 + q * 4 + j;
      if (grow < NNODES) h1[(size_t)grow * NCLS + t * 16 + l16] = acc2[t][j];
    }
  }
}

// ---------------------------------------------------------------------------
// CSR-by-dst build (degrees padded to multiple of 4; padding entries zeroed)
// ---------------------------------------------------------------------------
#define SCAN_NB 98   // ceil(100000 / 1024)

__global__ void k_hist(const int* __restrict__ dst, int* __restrict__ deg) {
  const int i = blockIdx.x * 256 + threadIdx.x;   // i < NEDGES/4
  const int4 d = ((const int4*)dst)[i];
  atomicAdd(&deg[d.x], 1);
  atomicAdd(&deg[d.y], 1);
  atomicAdd(&deg[d.z], 1);
  atomicAdd(&deg[d.w], 1);
}

__global__ void k_scan1(const int* __restrict__ deg, int* __restrict__ rowptr,
                        int* __restrict__ bsum) {
  __shared__ int s[256];
  const int t = threadIdx.x;
  const int base = blockIdx.x * 1024 + t * 4;
  int v0 = (base + 0 < NNODES) ? deg[base + 0] : 0;
  int v1 = (base + 1 < NNODES) ? deg[base + 1] : 0;
  int v2 = (base + 2 < NNODES) ? deg[base + 2] : 0;
  int v3 = (base + 3 < NNODES) ? deg[base + 3] : 0;
  v0 = (v0 + 3) & ~3; v1 = (v1 + 3) & ~3;        // pad each row to x4
  v2 = (v2 + 3) & ~3; v3 = (v3 + 3) & ~3;
  const int tsum = v0 + v1 + v2 + v3;
  s[t] = tsum;
  __syncthreads();
  for (int off = 1; off < 256; off <<= 1) {
    int x = (t >= off) ? s[t - off] : 0;
    __syncthreads();
    s[t] += x;
    __syncthreads();
  }
  const int excl = s[t] - tsum;
  if (t == 255) bsum[blockIdx.x] = s[255];
  if (base + 0 < NNODES) rowptr[base + 0] = excl;
  if (base + 1 < NNODES) rowptr[base + 1] = excl + v0;
  if (base + 2 < NNODES) rowptr[base + 2] = excl + v0 + v1;
  if (base + 3 < NNODES) rowptr[base + 3] = excl + v0 + v1 + v2;
}

__global__ void k_scan2(const int* __restrict__ bsum, int* __restrict__ bofs,
                        int* __restrict__ rowptr) {
  __shared__ int s[128];
  const int t = threadIdx.x;
  const int v = (t < SCAN_NB) ? bsum[t] : 0;
  s[t] = v;
  __syncthreads();
  for (int off = 1; off < 128; off <<= 1) {
    int x = (t >= off) ? s[t - off] : 0;
    __syncthreads();
    s[t] += x;
    __syncthreads();
  }
  if (t < SCAN_NB) bofs[t] = s[t] - v;
  if (t == 127) rowptr[NNODES] = s[127];   // total padded edges
}

__global__ void k_scan3(int* __restrict__ rowptr, const int* __restrict__ bofs,
                        int* __restrict__ nextpos) {
  const int i = blockIdx.x * 256 + threadIdx.x;
  if (i < NNODES) {
    const int r = rowptr[i] + bofs[i >> 10];
    rowptr[i] = r;
    nextpos[i] = r;
  }
}

// Fill interleaved (src, val) pairs so spmm streams metadata sequentially.
__global__ void k_fill(const int* __restrict__ dst, const int* __restrict__ src,
                       const float* __restrict__ val, int* __restrict__ nextpos,
                       int2* __restrict__ ecsr) {
  const int i = blockIdx.x * 256 + threadIdx.x;   // i < NEDGES/4
  const int4   d = ((const int4*)dst)[i];
  const int4   s = ((const int4*)src)[i];
  const float4 v = ((const float4*)val)[i];
  int p;
  p = atomicAdd(&nextpos[d.x], 1); ecsr[p] = make_int2(s.x, __float_as_int(v.x));
  p = atomicAdd(&nextpos[d.y], 1); ecsr[p] = make_int2(s.y, __float_as_int(v.y));
  p = atomicAdd(&nextpos[d.z], 1); ecsr[p] = make_int2(s.z, __float_as_int(v.z));
  p = atomicAdd(&nextpos[d.w], 1); ecsr[p] = make_int2(s.w, __float_as_int(v.w));
}

// ---------------------------------------------------------------------------
// SpMM gather: one wave per dst row, lane = output column (NC=64 == wave).
// Wave-uniform 4-edge scalar loads + 4 independent x-row gathers per group.
// ---------------------------------------------------------------------------
__global__ __launch_bounds__(256, 8)
void k_spmm(const int* __restrict__ rowptr, const int2* __restrict__ ecsr,
            const float* __restrict__ x, float* __restrict__ y) {
  const int wl   = (blockIdx.x * 256 + threadIdx.x) >> 6;
  const int w    = __builtin_amdgcn_readfirstlane(wl);
  const int lane = threadIdx.x & 63;
  const int beg = rowptr[w];
  const int end = rowptr[w + 1];
  float acc = 0.f;
  for (int i = beg; i < end; i += 4) {            // degree padded to x4
    const int2 e0 = ecsr[i + 0];
    const int2 e1 = ecsr[i + 1];
    const int2 e2 = ecsr[i + 2];
    const int2 e3 = ecsr[i + 3];
    const float x0 = x[(size_t)e0.x * NCLS + lane];
    const float x1 = x[(size_t)e1.x * NCLS + lane];
    const float x2 = x[(size_t)e2.x * NCLS + lane];
    const float x3 = x[(size_t)e3.x * NCLS + lane];
    acc += __int_as_float(e0.y) * x0;
    acc += __int_as_float(e1.y) * x1;
    acc += __int_as_float(e2.y) * x2;
    acc += __int_as_float(e3.y) * x3;
  }
  y[(size_t)w * NCLS + lane] = acc;
}

// ---------------------------------------------------------------------------
extern "C" void kernel_launch(void* const* d_in, const int* in_sizes, int n_in,
                              void* d_out, int out_size, void* d_ws, size_t ws_size,
                              hipStream_t stream) {
  const float* feat = (const float*)d_in[0];
  const float* W0   = (const float*)d_in[1];
  const float* W1   = (const float*)d_in[2];
  const float* eval = (const float*)d_in[3];
  const int*   esrc = (const int*)d_in[4];
  const int*   edst = (const int*)d_in[5];
  float* out = (float*)d_out;

  // Workspace carve-up (~55.5 MB; round 1 used 65.2 MB successfully)
  char* p = (char*)d_ws;
  float*  h1      = (float*)p;  p += 25600000;           // N*64*4
  int2*   ecsr    = (int2*)p;   p += (size_t)PADCAP * 8; // 28 MB
  int*    deg     = (int*)p;    p += 400128;
  int*    rowptr  = (int*)p;    p += 400384;             // N+1 ints
  int*    nextpos = (int*)p;    p += 400128;
  int*    bsum    = (int*)p;    p += 512;
  int*    bofs    = (int*)p;    p += 512;
  __bf16* W0T     = (__bf16*)p; p += 131072;             // 128x512 bf16
  __bf16* W1T     = (__bf16*)p; p += 16384;              // 64x128 bf16

  hipMemsetAsync(deg, 0, NNODES * sizeof(int), stream);
  hipMemsetAsync(ecsr, 0, (size_t)PADCAP * 8, stream);   // zero padding edges
  k_hist <<<NEDGES / 1024, 256, 0, stream>>>(edst, deg);
  k_scan1<<<SCAN_NB, 256, 0, stream>>>(deg, rowptr, bsum);
  k_scan2<<<1, 128, 0, stream>>>(bsum, bofs, rowptr);
  k_scan3<<<(NNODES + 255) / 256, 256, 0, stream>>>(rowptr, bofs, nextpos);
  k_fill <<<NEDGES / 1024, 256, 0, stream>>>(edst, esrc, eval, nextpos, ecsr);

  k_wcvt<<<256, 256, 0, stream>>>(W0, W1, W0T, W1T);
  gemm_fused<<<(NNODES + 63) / 64, 256, 0, stream>>>(feat, W0T, W1T, out);

  k_spmm<<<NNODES / 4, 256, 0, stream>>>(rowptr, ecsr, out, h1);   // layer 1
  k_spmm<<<NNODES / 4, 256, 0, stream>>>(rowptr, ecsr, h1, out);   // layer 2

  (void)in_sizes; (void)n_in; (void)out_size; (void)ws_size;
}

// Round 3
// 663.642 us; speedup vs baseline: 2.4955x; 1.2746x over previous
//
#include <hip/hip_runtime.h>
#include <hip/hip_bf16.h>

// Problem constants (match reference)
#define NNODES 100000
#define NEDGES 3200000
#define INDIM  512
#define HID    128
#define NCLS   64

// Bucketed CSR build
#define NBUCK  256
#define NPB    391                         // nodes per bucket; 256*391 = 100096
#define NCAP   (NBUCK * NPB)               // 100096
#define CHUNK  8192
#define NCHUNKB ((NEDGES + CHUNK - 1) / CHUNK)   // 391 blocks
#define PADCAP (NEDGES + 3 * NCAP)         // 3,500,288 max padded edges

typedef __bf16 bf16x8 __attribute__((ext_vector_type(8)));
typedef float  f32x4  __attribute__((ext_vector_type(4)));

#define APAD 40    // k-pad for 32-wide k tiles (80B row stride, 16B-aligned)
#define HPAD 136   // k-pad for 128-wide k (272B stride, 16B-aligned)

// ---------------------------------------------------------------------------
// Phase A1: per-block bucket histogram; reserve within-bucket runs.
// ---------------------------------------------------------------------------
__global__ __launch_bounds__(256)
void kA_count(const int* __restrict__ dst, int* __restrict__ gcnt,
              int* __restrict__ my_base) {
  __shared__ int cnt[NBUCK];
  const int t = threadIdx.x;
  cnt[t] = 0;
  __syncthreads();
  const int base = blockIdx.x * CHUNK;
#pragma unroll
  for (int j = 0; j < CHUNK / 1024; ++j) {
    const int e = base + (j * 256 + t) * 4;
    if (e < NEDGES) {                       // NEDGES%4==0 => full int4 ok
      const int4 d = *(const int4*)&dst[e];
      atomicAdd(&cnt[(unsigned)d.x / NPB], 1);
      atomicAdd(&cnt[(unsigned)d.y / NPB], 1);
      atomicAdd(&cnt[(unsigned)d.z / NPB], 1);
      atomicAdd(&cnt[(unsigned)d.w / NPB], 1);
    }
  }
  __syncthreads();
  my_base[blockIdx.x * NBUCK + t] = atomicAdd(&gcnt[t], cnt[t]);
}

// ---------------------------------------------------------------------------
// Phase A2: exclusive scan of bucket totals -> bucket segment bases.
// ---------------------------------------------------------------------------
__global__ void kA_bscan(const int* __restrict__ gcnt, int* __restrict__ bbase) {
  __shared__ int s[256];
  const int t = threadIdx.x;
  const int v = gcnt[t];
  s[t] = v;
  __syncthreads();
  for (int off = 1; off < 256; off <<= 1) {
    int x = (t >= off) ? s[t - off] : 0;
    __syncthreads();
    s[t] += x;
    __syncthreads();
  }
  bbase[t] = s[t] - v;
  if (t == 255) bbase[256] = s[255];        // == NEDGES
}

// ---------------------------------------------------------------------------
// Phase A3: scatter edges into bucket segments (run-coalesced writes).
// ---------------------------------------------------------------------------
__global__ __launch_bounds__(256)
void kA_scatter(const int* __restrict__ dst, const int* __restrict__ src,
                const float* __restrict__ val, const int* __restrict__ bbase,
                const int* __restrict__ my_base, int2* __restrict__ bsv,
                int* __restrict__ bdst) {
  __shared__ int cur[NBUCK];
  const int t = threadIdx.x;
  cur[t] = bbase[t] + my_base[blockIdx.x * NBUCK + t];
  __syncthreads();
  const int base = blockIdx.x * CHUNK;
#pragma unroll
  for (int j = 0; j < CHUNK / 1024; ++j) {
    const int e = base + (j * 256 + t) * 4;
    if (e < NEDGES) {
      const int4   d  = *(const int4*)&dst[e];
      const int4   sc = *(const int4*)&src[e];
      const float4 vv = *(const float4*)&val[e];
      int p;
      p = atomicAdd(&cur[(unsigned)d.x / NPB], 1);
      bsv[p] = make_int2(sc.x, __float_as_int(vv.x)); bdst[p] = d.x;
      p = atomicAdd(&cur[(unsigned)d.y / NPB], 1);
      bsv[p] = make_int2(sc.y, __float_as_int(vv.y)); bdst[p] = d.y;
      p = atomicAdd(&cur[(unsigned)d.z / NPB], 1);
      bsv[p] = make_int2(sc.z, __float_as_int(vv.z)); bdst[p] = d.z;
      p = atomicAdd(&cur[(unsigned)d.w / NPB], 1);
      bsv[p] = make_int2(sc.w, __float_as_int(vv.w)); bdst[p] = d.w;
    }
  }
}

// ---------------------------------------------------------------------------
// Phase B1: per-bucket node degrees (LDS histogram) + padded bucket totals.
// ---------------------------------------------------------------------------
__global__ __launch_bounds__(256)
void kB1(const int* __restrict__ bdst, const int* __restrict__ bbase,
         int* __restrict__ deg, int* __restrict__ pbt) {
  __shared__ int dl[NPB];
  __shared__ int s[256];
  const int t = threadIdx.x;
  const int b = blockIdx.x;
  const int nb = b * NPB;
  for (int i = t; i < NPB; i += 256) dl[i] = 0;
  __syncthreads();
  const int beg = bbase[b], end = bbase[b + 1];
  for (int e = beg + t; e < end; e += 256) atomicAdd(&dl[bdst[e] - nb], 1);
  __syncthreads();
  int psum = 0;
  for (int i = t; i < NPB; i += 256) { deg[nb + i] = dl[i]; psum += (dl[i] + 3) & ~3; }
  s[t] = psum;
  __syncthreads();
  for (int off = 1; off < 256; off <<= 1) {
    int x = (t >= off) ? s[t - off] : 0;
    __syncthreads();
    s[t] += x;
    __syncthreads();
  }
  if (t == 255) pbt[b] = s[255];
}

// ---------------------------------------------------------------------------
// Phase B2: scan padded bucket totals -> global padded bases; total rowptr.
// ---------------------------------------------------------------------------
__global__ void kB2(const int* __restrict__ pbt, int* __restrict__ pbase,
                    int* __restrict__ rowptr) {
  __shared__ int s[256];
  const int t = threadIdx.x;
  const int v = pbt[t];
  s[t] = v;
  __syncthreads();
  for (int off = 1; off < 256; off <<= 1) {
    int x = (t >= off) ? s[t - off] : 0;
    __syncthreads();
    s[t] += x;
    __syncthreads();
  }
  pbase[t] = s[t] - v;
  if (t == 255) rowptr[NNODES] = s[255];
}

// ---------------------------------------------------------------------------
// Phase B3: per-bucket fill. LDS cursors; writes confined to ~110KB region.
// ---------------------------------------------------------------------------
__global__ __launch_bounds__(256)
void kB3(const int2* __restrict__ bsv, const int* __restrict__ bdst,
         const int* __restrict__ bbase, const int* __restrict__ deg,
         const int* __restrict__ pbase, int* __restrict__ rowptr,
         int2* __restrict__ ecsr) {
  __shared__ int cur[NPB];
  __shared__ int s[256];
  const int t = threadIdx.x;
  const int b = blockIdx.x;
  const int nb = b * NPB;
  const int i0 = t * 2, i1 = t * 2 + 1;
  int d0 = 0, d1 = 0;
  if (i0 < NPB) d0 = deg[nb + i0];
  if (i1 < NPB) d1 = deg[nb + i1];
  const int p0 = (d0 + 3) & ~3, p1 = (d1 + 3) & ~3;
  const int tsum = p0 + p1;
  s[t] = tsum;
  __syncthreads();
  for (int off = 1; off < 256; off <<= 1) {
    int x = (t >= off) ? s[t - off] : 0;
    __syncthreads();
    s[t] += x;
    __syncthreads();
  }
  const int excl = s[t] - tsum;
  const int gb = pbase[b];
  const int2 z2 = make_int2(0, 0);
  if (i0 < NPB) {
    const int c = gb + excl;
    cur[i0] = c;
    if (nb + i0 < NNODES) rowptr[nb + i0] = c;
    for (int k = d0; k < p0; ++k) ecsr[c + k] = z2;   // zero padding entries
  }
  if (i1 < NPB) {
    const int c = gb + excl + p0;
    cur[i1] = c;
    if (nb + i1 < NNODES) rowptr[nb + i1] = c;
    for (int k = d1; k < p1; ++k) ecsr[c + k] = z2;
  }
  __syncthreads();
  const int beg = bbase[b], end = bbase[b + 1];
  for (int e = beg + t; e < end; e += 256) {
    const int2 sv = bsv[e];
    const int ld = bdst[e] - nb;
    const int p = atomicAdd(&cur[ld], 1);             // LDS atomic
    ecsr[p] = sv;
  }
}

// ---------------------------------------------------------------------------
// One-shot weight transpose + bf16 convert: W0T[n=128][k=512], W1T[n=64][k=128]
// ---------------------------------------------------------------------------
__global__ void k_wcvt(const float* __restrict__ W0, const float* __restrict__ W1,
                       __bf16* __restrict__ W0T, __bf16* __restrict__ W1T) {
  const int i = blockIdx.x * 256 + threadIdx.x;
  if (i < 65536) {              // W0 is [512][128]
    const int n = i >> 9, k = i & 511;
    W0T[i] = (__bf16)W0[k * HID + n];
  }
  if (i < 8192) {               // W1 is [128][64]
    const int n = i >> 7, k = i & 127;
    W1T[i] = (__bf16)W1[k * NCLS + n];
  }
}

// ---------------------------------------------------------------------------
// Fused dense phase: h1 = relu(X @ W0) @ W1   (bf16 MFMA, fp32 accumulate)
// ---------------------------------------------------------------------------
__global__ __launch_bounds__(256, 4)
void gemm_fused(const float* __restrict__ feat, const __bf16* __restrict__ W0T,
                const __bf16* __restrict__ W1T, float* __restrict__ h1) {
  __shared__ __bf16 Bs[HID * APAD];     // W0T k-tile [n=128][k=32 pad 40]
  __shared__ __bf16 h0s[64 * HPAD];     // relu(X@W0) tile, A-operand layout

  const int tid  = threadIdx.x;
  const int wave = tid >> 6;
  const int lane = tid & 63;
  const int q    = lane >> 4;
  const int l16  = lane & 15;
  const int rb   = blockIdx.x * 64;

  int row = rb + wave * 16 + l16;
  if (row >= NNODES) row = NNODES - 1;          // clamped loads; stores guarded
  const float* __restrict__ arow = feat + (size_t)row * INDIM;

  f32x4 acc[8];
#pragma unroll
  for (int t = 0; t < 8; ++t) acc[t] = (f32x4){0.f, 0.f, 0.f, 0.f};

  for (int kk = 0; kk < INDIM / 32; ++kk) {
    const int k0 = kk * 32;
#pragma unroll
    for (int i = 0; i < 2; ++i) {
      const int c  = tid + i * 256;
      const int n  = c >> 2;
      const int ko = (c & 3) * 8;
      *(bf16x8*)&Bs[n * APAD + ko] = *(const bf16x8*)&W0T[n * INDIM + k0 + ko];
    }
    const float4 a0 = *(const float4*)&arow[k0 + q * 8];
    const float4 a1 = *(const float4*)&arow[k0 + q * 8 + 4];
    bf16x8 aF;
    aF[0] = (__bf16)a0.x; aF[1] = (__bf16)a0.y; aF[2] = (__bf16)a0.z; aF[3] = (__bf16)a0.w;
    aF[4] = (__bf16)a1.x; aF[5] = (__bf16)a1.y; aF[6] = (__bf16)a1.z; aF[7] = (__bf16)a1.w;
    __syncthreads();
#pragma unroll
    for (int t = 0; t < 8; ++t) {
      const bf16x8 bF = *(const bf16x8*)&Bs[(t * 16 + l16) * APAD + q * 8];
      acc[t] = __builtin_amdgcn_mfma_f32_16x16x32_bf16(aF, bF, acc[t], 0, 0, 0);
    }
    __syncthreads();
  }

  // ReLU + cvt -> h0s in A-operand layout (C/D: row=q*4+j, col=l16)
#pragma unroll
  for (int t = 0; t < 8; ++t) {
#pragma unroll
    for (int j = 0; j < 4; ++j) {
      float v = acc[t][j];
      v = v > 0.f ? v : 0.f;
      h0s[(wave * 16 + q * 4 + j) * HPAD + t * 16 + l16] = (__bf16)v;
    }
  }

  f32x4 acc2[4];
#pragma unroll
  for (int t = 0; t < 4; ++t) acc2[t] = (f32x4){0.f, 0.f, 0.f, 0.f};
#pragma unroll
  for (int kk = 0; kk < HID / 32; ++kk) {
    const bf16x8 aF = *(const bf16x8*)&h0s[(wave * 16 + l16) * HPAD + kk * 32 + q * 8];
#pragma unroll
    for (int t = 0; t < 4; ++t) {
      const bf16x8 bF = *(const bf16x8*)&W1T[(t * 16 + l16) * HID + kk * 32 + q * 8];
      acc2[t] = __builtin_amdgcn_mfma_f32_16x16x32_bf16(aF, bF, acc2[t], 0, 0, 0);
    }
  }

#pragma unroll
  for (int t = 0; t < 4; ++t) {
#pragma unroll
    for (int j = 0; j < 4; ++j) {
      const int grow = rb + wave * 16 + q * 4 + j;
      if (grow < NNODES) h1[(size_t)grow * NCLS + t * 16 + l16] = acc2[t][j];
    }
  }
}

// ---------------------------------------------------------------------------
// SpMM gather: one wave per dst row, lane = output column (NC=64 == wave).
// ---------------------------------------------------------------------------
__global__ __launch_bounds__(256, 8)
void k_spmm(const int* __restrict__ rowptr, const int2* __restrict__ ecsr,
            const float* __restrict__ x, float* __restrict__ y) {
  const int wl   = (blockIdx.x * 256 + threadIdx.x) >> 6;
  const int w    = __builtin_amdgcn_readfirstlane(wl);
  const int lane = threadIdx.x & 63;
  const int beg = rowptr[w];
  const int end = rowptr[w + 1];
  float acc = 0.f;
  for (int i = beg; i < end; i += 4) {            // degree padded to x4
    const int2 e0 = ecsr[i + 0];
    const int2 e1 = ecsr[i + 1];
    const int2 e2 = ecsr[i + 2];
    const int2 e3 = ecsr[i + 3];
    const float x0 = x[(size_t)e0.x * NCLS + lane];
    const float x1 = x[(size_t)e1.x * NCLS + lane];
    const float x2 = x[(size_t)e2.x * NCLS + lane];
    const float x3 = x[(size_t)e3.x * NCLS + lane];
    acc += __int_as_float(e0.y) * x0;
    acc += __int_as_float(e1.y) * x1;
    acc += __int_as_float(e2.y) * x2;
    acc += __int_as_float(e3.y) * x3;
  }
  y[(size_t)w * NCLS + lane] = acc;
}

// ---------------------------------------------------------------------------
extern "C" void kernel_launch(void* const* d_in, const int* in_sizes, int n_in,
                              void* d_out, int out_size, void* d_ws, size_t ws_size,
                              hipStream_t stream) {
  const float* feat = (const float*)d_in[0];
  const float* W0   = (const float*)d_in[1];
  const float* W1   = (const float*)d_in[2];
  const float* eval = (const float*)d_in[3];
  const int*   esrc = (const int*)d_in[4];
  const int*   edst = (const int*)d_in[5];
  float* out = (float*)d_out;

  // Workspace (~54.2 MB; 65.2 MB proven OK in round 1).
  // bsv lives in d_out (exactly 25.6 MB, dead before gemm writes d_out).
  // h1 overlays the dead binning arrays (bdst/deg/my_base/...).
  char* p = (char*)d_ws;
  int2* ecsr   = (int2*)p;           p += (size_t)PADCAP * 8;   // 28,002,304
  char* X      = p;                  p += 25600000;             // h1 overlay
  int*  rowptr = (int*)p;            p += 400128;               // N+1 ints
  __bf16* W0T  = (__bf16*)p;         p += 131072;
  __bf16* W1T  = (__bf16*)p;         p += 16384;

  float* h1      = (float*)X;
  int*   bdst    = (int*)X;                                     // 12,800,000
  int*   deg     = (int*)(X + 12800000);                        // 400,384
  int*   my_base = (int*)(X + 13200384);                        // 400,384
  int*   gcnt    = (int*)(X + 13600768);                        // 1024
  int*   pbt     = (int*)(X + 13601792);                        // 1024
  int*   bbase   = (int*)(X + 13602816);                        // 1280
  int*   pbase   = (int*)(X + 13604096);                        // 1280
  int2*  bsv     = (int2*)d_out;                                // 25,600,000

  hipMemsetAsync(gcnt, 0, NBUCK * sizeof(int), stream);
  kA_count  <<<NCHUNKB, 256, 0, stream>>>(edst, gcnt, my_base);
  kA_bscan  <<<1, 256, 0, stream>>>(gcnt, bbase);
  kA_scatter<<<NCHUNKB, 256, 0, stream>>>(edst, esrc, eval, bbase, my_base, bsv, bdst);
  kB1       <<<NBUCK, 256, 0, stream>>>(bdst, bbase, deg, pbt);
  kB2       <<<1, 256, 0, stream>>>(pbt, pbase, rowptr);
  kB3       <<<NBUCK, 256, 0, stream>>>(bsv, bdst, bbase, deg, pbase, rowptr, ecsr);

  k_wcvt<<<256, 256, 0, stream>>>(W0, W1, W0T, W1T);
  gemm_fused<<<(NNODES + 63) / 64, 256, 0, stream>>>(feat, W0T, W1T, out);

  k_spmm<<<NNODES / 4, 256, 0, stream>>>(rowptr, ecsr, out, h1);   // layer 1
  k_spmm<<<NNODES / 4, 256, 0, stream>>>(rowptr, ecsr, h1, out);   // layer 2

  (void)in_sizes; (void)n_in; (void)out_size; (void)ws_size;
}

// Round 4
// 608.610 us; speedup vs baseline: 2.7211x; 1.0904x over previous
//
#include <hip/hip_runtime.h>
#include <hip/hip_bf16.h>

// Problem constants (match reference)
#define NNODES 100000
#define NEDGES 3200000
#define INDIM  512
#define HID    128
#define NCLS   64

// Bucketed CSR build
#define NBUCK  256
#define NPB    391                         // nodes per bucket; 256*391 = 100096
#define NCAP   (NBUCK * NPB)               // 100096
#define CHUNK  8192
#define NCHUNKB ((NEDGES + CHUNK - 1) / CHUNK)   // 391 blocks
#define PADCAP (NEDGES + 3 * NCAP)         // 3,500,288 max padded edges

typedef __bf16 bf16x8 __attribute__((ext_vector_type(8)));
typedef float  f32x4  __attribute__((ext_vector_type(4)));

#define APAD 40    // k-pad for 32-wide k tiles (80B row stride, 16B-aligned)
#define HPAD 136   // k-pad for 128-wide k (272B stride, 16B-aligned)

// ---------------------------------------------------------------------------
// Phase A1: per-block bucket histogram; reserve within-bucket runs.
// ---------------------------------------------------------------------------
__global__ __launch_bounds__(256)
void kA_count(const int* __restrict__ dst, int* __restrict__ gcnt,
              int* __restrict__ my_base) {
  __shared__ int cnt[NBUCK];
  const int t = threadIdx.x;
  cnt[t] = 0;
  __syncthreads();
  const int base = blockIdx.x * CHUNK;
#pragma unroll
  for (int j = 0; j < CHUNK / 1024; ++j) {
    const int e = base + (j * 256 + t) * 4;
    if (e < NEDGES) {                       // NEDGES%4==0 => full int4 ok
      const int4 d = *(const int4*)&dst[e];
      atomicAdd(&cnt[(unsigned)d.x / NPB], 1);
      atomicAdd(&cnt[(unsigned)d.y / NPB], 1);
      atomicAdd(&cnt[(unsigned)d.z / NPB], 1);
      atomicAdd(&cnt[(unsigned)d.w / NPB], 1);
    }
  }
  __syncthreads();
  my_base[blockIdx.x * NBUCK + t] = atomicAdd(&gcnt[t], cnt[t]);
}

// ---------------------------------------------------------------------------
// Phase A2: exclusive scan of bucket totals -> bucket segment bases.
// ---------------------------------------------------------------------------
__global__ void kA_bscan(const int* __restrict__ gcnt, int* __restrict__ bbase) {
  __shared__ int s[256];
  const int t = threadIdx.x;
  const int v = gcnt[t];
  s[t] = v;
  __syncthreads();
  for (int off = 1; off < 256; off <<= 1) {
    int x = (t >= off) ? s[t - off] : 0;
    __syncthreads();
    s[t] += x;
    __syncthreads();
  }
  bbase[t] = s[t] - v;
  if (t == 255) bbase[256] = s[255];        // == NEDGES
}

// ---------------------------------------------------------------------------
// Phase A3: scatter edges into bucket segments (run-coalesced writes).
// ---------------------------------------------------------------------------
__global__ __launch_bounds__(256)
void kA_scatter(const int* __restrict__ dst, const int* __restrict__ src,
                const float* __restrict__ val, const int* __restrict__ bbase,
                const int* __restrict__ my_base, int2* __restrict__ bsv,
                int* __restrict__ bdst) {
  __shared__ int cur[NBUCK];
  const int t = threadIdx.x;
  cur[t] = bbase[t] + my_base[blockIdx.x * NBUCK + t];
  __syncthreads();
  const int base = blockIdx.x * CHUNK;
#pragma unroll
  for (int j = 0; j < CHUNK / 1024; ++j) {
    const int e = base + (j * 256 + t) * 4;
    if (e < NEDGES) {
      const int4   d  = *(const int4*)&dst[e];
      const int4   sc = *(const int4*)&src[e];
      const float4 vv = *(const float4*)&val[e];
      int p;
      p = atomicAdd(&cur[(unsigned)d.x / NPB], 1);
      bsv[p] = make_int2(sc.x, __float_as_int(vv.x)); bdst[p] = d.x;
      p = atomicAdd(&cur[(unsigned)d.y / NPB], 1);
      bsv[p] = make_int2(sc.y, __float_as_int(vv.y)); bdst[p] = d.y;
      p = atomicAdd(&cur[(unsigned)d.z / NPB], 1);
      bsv[p] = make_int2(sc.z, __float_as_int(vv.z)); bdst[p] = d.z;
      p = atomicAdd(&cur[(unsigned)d.w / NPB], 1);
      bsv[p] = make_int2(sc.w, __float_as_int(vv.w)); bdst[p] = d.w;
    }
  }
}

// ---------------------------------------------------------------------------
// Phase B1: per-bucket node degrees (LDS histogram) + padded bucket totals.
// ---------------------------------------------------------------------------
__global__ __launch_bounds__(256)
void kB1(const int* __restrict__ bdst, const int* __restrict__ bbase,
         int* __restrict__ deg, int* __restrict__ pbt) {
  __shared__ int dl[NPB];
  __shared__ int s[256];
  const int t = threadIdx.x;
  const int b = blockIdx.x;
  const int nb = b * NPB;
  for (int i = t; i < NPB; i += 256) dl[i] = 0;
  __syncthreads();
  const int beg = bbase[b], end = bbase[b + 1];
  for (int e = beg + t; e < end; e += 256) atomicAdd(&dl[bdst[e] - nb], 1);
  __syncthreads();
  int psum = 0;
  for (int i = t; i < NPB; i += 256) { deg[nb + i] = dl[i]; psum += (dl[i] + 3) & ~3; }
  s[t] = psum;
  __syncthreads();
  for (int off = 1; off < 256; off <<= 1) {
    int x = (t >= off) ? s[t - off] : 0;
    __syncthreads();
    s[t] += x;
    __syncthreads();
  }
  if (t == 255) pbt[b] = s[255];
}

// ---------------------------------------------------------------------------
// Phase B2: scan padded bucket totals -> global padded bases; total rowptr.
// ---------------------------------------------------------------------------
__global__ void kB2(const int* __restrict__ pbt, int* __restrict__ pbase,
                    int* __restrict__ rowptr) {
  __shared__ int s[256];
  const int t = threadIdx.x;
  const int v = pbt[t];
  s[t] = v;
  __syncthreads();
  for (int off = 1; off < 256; off <<= 1) {
    int x = (t >= off) ? s[t - off] : 0;
    __syncthreads();
    s[t] += x;
    __syncthreads();
  }
  pbase[t] = s[t] - v;
  if (t == 255) rowptr[NNODES] = s[255];
}

// ---------------------------------------------------------------------------
// Phase B3: per-bucket fill. LDS cursors; writes confined to ~110KB region.
// ---------------------------------------------------------------------------
__global__ __launch_bounds__(256)
void kB3(const int2* __restrict__ bsv, const int* __restrict__ bdst,
         const int* __restrict__ bbase, const int* __restrict__ deg,
         const int* __restrict__ pbase, int* __restrict__ rowptr,
         int2* __restrict__ ecsr) {
  __shared__ int cur[NPB];
  __shared__ int s[256];
  const int t = threadIdx.x;
  const int b = blockIdx.x;
  const int nb = b * NPB;
  const int i0 = t * 2, i1 = t * 2 + 1;
  int d0 = 0, d1 = 0;
  if (i0 < NPB) d0 = deg[nb + i0];
  if (i1 < NPB) d1 = deg[nb + i1];
  const int p0 = (d0 + 3) & ~3, p1 = (d1 + 3) & ~3;
  const int tsum = p0 + p1;
  s[t] = tsum;
  __syncthreads();
  for (int off = 1; off < 256; off <<= 1) {
    int x = (t >= off) ? s[t - off] : 0;
    __syncthreads();
    s[t] += x;
    __syncthreads();
  }
  const int excl = s[t] - tsum;
  const int gb = pbase[b];
  const int2 z2 = make_int2(0, 0);
  if (i0 < NPB) {
    const int c = gb + excl;
    cur[i0] = c;
    if (nb + i0 < NNODES) rowptr[nb + i0] = c;
    for (int k = d0; k < p0; ++k) ecsr[c + k] = z2;   // zero padding entries
  }
  if (i1 < NPB) {
    const int c = gb + excl + p0;
    cur[i1] = c;
    if (nb + i1 < NNODES) rowptr[nb + i1] = c;
    for (int k = d1; k < p1; ++k) ecsr[c + k] = z2;
  }
  __syncthreads();
  const int beg = bbase[b], end = bbase[b + 1];
  for (int e = beg + t; e < end; e += 256) {
    const int2 sv = bsv[e];
    const int ld = bdst[e] - nb;
    const int p = atomicAdd(&cur[ld], 1);             // LDS atomic
    ecsr[p] = sv;
  }
}

// ---------------------------------------------------------------------------
// One-shot weight transpose + bf16 convert: W0T[n=128][k=512], W1T[n=64][k=128]
// ---------------------------------------------------------------------------
__global__ void k_wcvt(const float* __restrict__ W0, const float* __restrict__ W1,
                       __bf16* __restrict__ W0T, __bf16* __restrict__ W1T) {
  const int i = blockIdx.x * 256 + threadIdx.x;
  if (i < 65536) {              // W0 is [512][128]
    const int n = i >> 9, k = i & 511;
    W0T[i] = (__bf16)W0[k * HID + n];
  }
  if (i < 8192) {               // W1 is [128][64]
    const int n = i >> 7, k = i & 127;
    W1T[i] = (__bf16)W1[k * NCLS + n];
  }
}

// ---------------------------------------------------------------------------
// Fused dense phase: h1 = relu(X @ W0) @ W1  (bf16 MFMA), h1 stored as bf16
// ---------------------------------------------------------------------------
__global__ __launch_bounds__(256, 4)
void gemm_fused(const float* __restrict__ feat, const __bf16* __restrict__ W0T,
                const __bf16* __restrict__ W1T, __bf16* __restrict__ h1b) {
  __shared__ __bf16 Bs[HID * APAD];     // W0T k-tile [n=128][k=32 pad 40]
  __shared__ __bf16 h0s[64 * HPAD];     // relu(X@W0) tile, A-operand layout

  const int tid  = threadIdx.x;
  const int wave = tid >> 6;
  const int lane = tid & 63;
  const int q    = lane >> 4;
  const int l16  = lane & 15;
  const int rb   = blockIdx.x * 64;

  int row = rb + wave * 16 + l16;
  if (row >= NNODES) row = NNODES - 1;          // clamped loads; stores guarded
  const float* __restrict__ arow = feat + (size_t)row * INDIM;

  f32x4 acc[8];
#pragma unroll
  for (int t = 0; t < 8; ++t) acc[t] = (f32x4){0.f, 0.f, 0.f, 0.f};

  for (int kk = 0; kk < INDIM / 32; ++kk) {
    const int k0 = kk * 32;
#pragma unroll
    for (int i = 0; i < 2; ++i) {
      const int c  = tid + i * 256;
      const int n  = c >> 2;
      const int ko = (c & 3) * 8;
      *(bf16x8*)&Bs[n * APAD + ko] = *(const bf16x8*)&W0T[n * INDIM + k0 + ko];
    }
    const float4 a0 = *(const float4*)&arow[k0 + q * 8];
    const float4 a1 = *(const float4*)&arow[k0 + q * 8 + 4];
    bf16x8 aF;
    aF[0] = (__bf16)a0.x; aF[1] = (__bf16)a0.y; aF[2] = (__bf16)a0.z; aF[3] = (__bf16)a0.w;
    aF[4] = (__bf16)a1.x; aF[5] = (__bf16)a1.y; aF[6] = (__bf16)a1.z; aF[7] = (__bf16)a1.w;
    __syncthreads();
#pragma unroll
    for (int t = 0; t < 8; ++t) {
      const bf16x8 bF = *(const bf16x8*)&Bs[(t * 16 + l16) * APAD + q * 8];
      acc[t] = __builtin_amdgcn_mfma_f32_16x16x32_bf16(aF, bF, acc[t], 0, 0, 0);
    }
    __syncthreads();
  }

  // ReLU + cvt -> h0s in A-operand layout (C/D: row=q*4+j, col=l16)
#pragma unroll
  for (int t = 0; t < 8; ++t) {
#pragma unroll
    for (int j = 0; j < 4; ++j) {
      float v = acc[t][j];
      v = v > 0.f ? v : 0.f;
      h0s[(wave * 16 + q * 4 + j) * HPAD + t * 16 + l16] = (__bf16)v;
    }
  }

  f32x4 acc2[4];
#pragma unroll
  for (int t = 0; t < 4; ++t) acc2[t] = (f32x4){0.f, 0.f, 0.f, 0.f};
#pragma unroll
  for (int kk = 0; kk < HID / 32; ++kk) {
    const bf16x8 aF = *(const bf16x8*)&h0s[(wave * 16 + l16) * HPAD + kk * 32 + q * 8];
#pragma unroll
    for (int t = 0; t < 4; ++t) {
      const bf16x8 bF = *(const bf16x8*)&W1T[(t * 16 + l16) * HID + kk * 32 + q * 8];
      acc2[t] = __builtin_amdgcn_mfma_f32_16x16x32_bf16(aF, bF, acc2[t], 0, 0, 0);
    }
  }

#pragma unroll
  for (int t = 0; t < 4; ++t) {
#pragma unroll
    for (int j = 0; j < 4; ++j) {
      const int grow = rb + wave * 16 + q * 4 + j;
      if (grow < NNODES)
        h1b[(size_t)grow * NCLS + t * 16 + l16] = (__bf16)acc2[t][j];
    }
  }
}

// ---------------------------------------------------------------------------
// SpMM gather: one wave per dst row, lane = output column. bf16 x-rows
// (128B/row = one full-line wave transaction), fp32 accumulate.
// ---------------------------------------------------------------------------
template <typename OUT_T>
__global__ __launch_bounds__(256, 8)
void k_spmm(const int* __restrict__ rowptr, const int2* __restrict__ ecsr,
            const __bf16* __restrict__ x, OUT_T* __restrict__ y) {
  const int wl   = (blockIdx.x * 256 + threadIdx.x) >> 6;
  const int w    = __builtin_amdgcn_readfirstlane(wl);
  const int lane = threadIdx.x & 63;
  const int beg = rowptr[w];
  const int end = rowptr[w + 1];
  float acc = 0.f;
  for (int i = beg; i < end; i += 4) {            // degree padded to x4, 32B-aligned
    const int4 m0 = *(const int4*)&ecsr[i];       // edges i, i+1
    const int4 m1 = *(const int4*)&ecsr[i + 2];   // edges i+2, i+3
    const float x0 = (float)x[(size_t)m0.x * NCLS + lane];
    const float x1 = (float)x[(size_t)m0.z * NCLS + lane];
    const float x2 = (float)x[(size_t)m1.x * NCLS + lane];
    const float x3 = (float)x[(size_t)m1.z * NCLS + lane];
    acc += __int_as_float(m0.y) * x0;
    acc += __int_as_float(m0.w) * x1;
    acc += __int_as_float(m1.y) * x2;
    acc += __int_as_float(m1.w) * x3;
  }
  y[(size_t)w * NCLS + lane] = (OUT_T)acc;
}

// ---------------------------------------------------------------------------
extern "C" void kernel_launch(void* const* d_in, const int* in_sizes, int n_in,
                              void* d_out, int out_size, void* d_ws, size_t ws_size,
                              hipStream_t stream) {
  const float* feat = (const float*)d_in[0];
  const float* W0   = (const float*)d_in[1];
  const float* W1   = (const float*)d_in[2];
  const float* eval = (const float*)d_in[3];
  const int*   esrc = (const int*)d_in[4];
  const int*   edst = (const int*)d_in[5];
  float* out = (float*)d_out;

  // Workspace (~55 MB; 65.2 MB proven OK in round 1).
  // bsv lives in d_out (25.6 MB, dead before final spmm writes d_out).
  // h1b (bf16, 12.8 MB) overlays the dead binning arrays.
  char* p = (char*)d_ws;
  int2*   ecsr   = (int2*)p;    p += (size_t)PADCAP * 8;   // 28,002,304
  char*   X      = p;           p += 13605376;             // binning / h1b overlay
  __bf16* h2b    = (__bf16*)p;  p += 12800000;
  int*    rowptr = (int*)p;     p += 400384;               // N+1 ints
  __bf16* W0T    = (__bf16*)p;  p += 131072;
  __bf16* W1T    = (__bf16*)p;  p += 16384;

  __bf16* h1b    = (__bf16*)X;                             // 12,800,000
  int*    bdst   = (int*)X;                                // 12,800,000
  int*    deg    = (int*)(X + 12800000);                   // 400,384
  int*    my_base= (int*)(X + 13200384);                   // 400,384
  int*    gcnt   = (int*)(X + 13600768);                   // 1024
  int*    pbt    = (int*)(X + 13601792);                   // 1024
  int*    bbase  = (int*)(X + 13602816);                   // 1280
  int*    pbase  = (int*)(X + 13604096);                   // 1280
  int2*   bsv    = (int2*)d_out;                           // 25,600,000

  hipMemsetAsync(gcnt, 0, NBUCK * sizeof(int), stream);
  kA_count  <<<NCHUNKB, 256, 0, stream>>>(edst, gcnt, my_base);
  kA_bscan  <<<1, 256, 0, stream>>>(gcnt, bbase);
  kA_scatter<<<NCHUNKB, 256, 0, stream>>>(edst, esrc, eval, bbase, my_base, bsv, bdst);
  kB1       <<<NBUCK, 256, 0, stream>>>(bdst, bbase, deg, pbt);
  kB2       <<<1, 256, 0, stream>>>(pbt, pbase, rowptr);
  kB3       <<<NBUCK, 256, 0, stream>>>(bsv, bdst, bbase, deg, pbase, rowptr, ecsr);

  k_wcvt<<<256, 256, 0, stream>>>(W0, W1, W0T, W1T);
  gemm_fused<<<(NNODES + 63) / 64, 256, 0, stream>>>(feat, W0T, W1T, h1b);

  k_spmm<__bf16><<<NNODES / 4, 256, 0, stream>>>(rowptr, ecsr, h1b, h2b);  // layer 1
  k_spmm<float> <<<NNODES / 4, 256, 0, stream>>>(rowptr, ecsr, h2b, out);  // layer 2

  (void)in_sizes; (void)n_in; (void)out_size; (void)ws_size;
}

// Round 5
// 572.303 us; speedup vs baseline: 2.8937x; 1.0634x over previous
//
#include <hip/hip_runtime.h>
#include <hip/hip_bf16.h>

// Problem constants (match reference)
#define NNODES 100000
#define NEDGES 3200000
#define INDIM  512
#define HID    128
#define NCLS   64

// Bucketed CSR build
#define NBUCK  256
#define NPB    391                         // nodes per bucket; 256*391 = 100096
#define NCAP   (NBUCK * NPB)               // 100096
#define BCAP   16384                       // fixed padded capacity per bucket
                                           // (worst case ~14.7k: Poisson(12500)+pad8)
#define CHUNK  8192
#define NCHUNKB ((NEDGES + CHUNK - 1) / CHUNK)   // 391 blocks

typedef __bf16 bf16x8 __attribute__((ext_vector_type(8)));
typedef float  f32x4  __attribute__((ext_vector_type(4)));

#define APAD 40    // k-pad for 32-wide k tiles (80B row stride, 16B-aligned)
#define HPAD 136   // k-pad for 128-wide k (272B stride, 16B-aligned)

// ---------------------------------------------------------------------------
// Fused: blocks 0..390 = per-chunk bucket histogram (reserve runs);
//        block 391     = weight transpose+bf16 convert (independent work).
// ---------------------------------------------------------------------------
__global__ __launch_bounds__(256)
void k_count_wcvt(const int* __restrict__ dst, int* __restrict__ gcnt,
                  int* __restrict__ my_base,
                  const float* __restrict__ W0, const float* __restrict__ W1,
                  __bf16* __restrict__ W0T, __bf16* __restrict__ W1T) {
  const int t = threadIdx.x;
  if (blockIdx.x == NCHUNKB) {
    for (int i = t; i < 65536; i += 256) {      // W0 [512][128] -> W0T[n][k]
      const int n = i >> 9, k = i & 511;
      W0T[i] = (__bf16)W0[k * HID + n];
    }
    for (int i = t; i < 8192; i += 256) {       // W1 [128][64] -> W1T[n][k]
      const int n = i >> 7, k = i & 127;
      W1T[i] = (__bf16)W1[k * NCLS + n];
    }
    return;
  }
  __shared__ int cnt[NBUCK];
  cnt[t] = 0;
  __syncthreads();
  const int base = blockIdx.x * CHUNK;
#pragma unroll
  for (int j = 0; j < CHUNK / 1024; ++j) {
    const int e = base + (j * 256 + t) * 4;
    if (e < NEDGES) {                           // NEDGES%4==0 => full int4 ok
      const int4 d = *(const int4*)&dst[e];
      atomicAdd(&cnt[(unsigned)d.x / NPB], 1);
      atomicAdd(&cnt[(unsigned)d.y / NPB], 1);
      atomicAdd(&cnt[(unsigned)d.z / NPB], 1);
      atomicAdd(&cnt[(unsigned)d.w / NPB], 1);
    }
  }
  __syncthreads();
  my_base[blockIdx.x * NBUCK + t] = atomicAdd(&gcnt[t], cnt[t]);
}

// ---------------------------------------------------------------------------
// Exclusive scan of bucket totals -> bsv segment bases.
// ---------------------------------------------------------------------------
__global__ void kA_bscan(const int* __restrict__ gcnt, int* __restrict__ bbase) {
  __shared__ int s[256];
  const int t = threadIdx.x;
  const int v = gcnt[t];
  s[t] = v;
  __syncthreads();
  for (int off = 1; off < 256; off <<= 1) {
    int x = (t >= off) ? s[t - off] : 0;
    __syncthreads();
    s[t] += x;
    __syncthreads();
  }
  bbase[t] = s[t] - v;
  if (t == 255) bbase[256] = s[255];            // == NEDGES
}

// ---------------------------------------------------------------------------
// Fused dispatch: blocks 0..390 = edge scatter into bucket runs (packs
// local-dst into src word: src | ldst<<17);  blocks 391.. = dense GEMM
// h1 = relu(X@W0)@W1 (bf16 MFMA). Independent work -> true overlap.
// ---------------------------------------------------------------------------
__global__ __launch_bounds__(256, 4)
void k_scatter_gemm(const int* __restrict__ dst, const int* __restrict__ src,
                    const float* __restrict__ val, const int* __restrict__ bbase,
                    const int* __restrict__ my_base, int2* __restrict__ bsv,
                    const float* __restrict__ feat, const __bf16* __restrict__ W0T,
                    const __bf16* __restrict__ W1T, __bf16* __restrict__ h1b) {
  __shared__ __align__(16) char smem[27648];
  const int tid = threadIdx.x;

  if (blockIdx.x < NCHUNKB) {
    // ---------------- scatter branch ----------------
    int* cur = (int*)smem;
    cur[tid] = bbase[tid] + my_base[blockIdx.x * NBUCK + tid];
    __syncthreads();
    const int base = blockIdx.x * CHUNK;
#pragma unroll
    for (int j = 0; j < CHUNK / 1024; ++j) {
      const int e = base + (j * 256 + tid) * 4;
      if (e < NEDGES) {
        const int4   d  = *(const int4*)&dst[e];
        const int4   sc = *(const int4*)&src[e];
        const float4 vv = *(const float4*)&val[e];
        int p, b, ld;
        b = (unsigned)d.x / NPB; ld = d.x - b * NPB;
        p = atomicAdd(&cur[b], 1);
        bsv[p] = make_int2(sc.x | (ld << 17), __float_as_int(vv.x));
        b = (unsigned)d.y / NPB; ld = d.y - b * NPB;
        p = atomicAdd(&cur[b], 1);
        bsv[p] = make_int2(sc.y | (ld << 17), __float_as_int(vv.y));
        b = (unsigned)d.z / NPB; ld = d.z - b * NPB;
        p = atomicAdd(&cur[b], 1);
        bsv[p] = make_int2(sc.z | (ld << 17), __float_as_int(vv.z));
        b = (unsigned)d.w / NPB; ld = d.w - b * NPB;
        p = atomicAdd(&cur[b], 1);
        bsv[p] = make_int2(sc.w | (ld << 17), __float_as_int(vv.w));
      }
    }
    return;
  }

  // ---------------- gemm branch ----------------
  __bf16* Bs  = (__bf16*)smem;                 // [128][40] = 10240 B
  __bf16* h0s = (__bf16*)(smem + 10240);       // [64][136] = 17408 B

  const int wave = tid >> 6;
  const int lane = tid & 63;
  const int q    = lane >> 4;
  const int l16  = lane & 15;
  const int rb   = (blockIdx.x - NCHUNKB) * 64;

  int row = rb + wave * 16 + l16;
  if (row >= NNODES) row = NNODES - 1;          // clamped loads; stores guarded
  const float* __restrict__ arow = feat + (size_t)row * INDIM;

  f32x4 acc[8];
#pragma unroll
  for (int t = 0; t < 8; ++t) acc[t] = (f32x4){0.f, 0.f, 0.f, 0.f};

  for (int kk = 0; kk < INDIM / 32; ++kk) {
    const int k0 = kk * 32;
#pragma unroll
    for (int i = 0; i < 2; ++i) {
      const int c  = tid + i * 256;
      const int n  = c >> 2;
      const int ko = (c & 3) * 8;
      *(bf16x8*)&Bs[n * APAD + ko] = *(const bf16x8*)&W0T[n * INDIM + k0 + ko];
    }
    const float4 a0 = *(const float4*)&arow[k0 + q * 8];
    const float4 a1 = *(const float4*)&arow[k0 + q * 8 + 4];
    bf16x8 aF;
    aF[0] = (__bf16)a0.x; aF[1] = (__bf16)a0.y; aF[2] = (__bf16)a0.z; aF[3] = (__bf16)a0.w;
    aF[4] = (__bf16)a1.x; aF[5] = (__bf16)a1.y; aF[6] = (__bf16)a1.z; aF[7] = (__bf16)a1.w;
    __syncthreads();
#pragma unroll
    for (int t = 0; t < 8; ++t) {
      const bf16x8 bF = *(const bf16x8*)&Bs[(t * 16 + l16) * APAD + q * 8];
      acc[t] = __builtin_amdgcn_mfma_f32_16x16x32_bf16(aF, bF, acc[t], 0, 0, 0);
    }
    __syncthreads();
  }

  // ReLU + cvt -> h0s in A-operand layout (C/D: row=q*4+j, col=l16)
#pragma unroll
  for (int t = 0; t < 8; ++t) {
#pragma unroll
    for (int j = 0; j < 4; ++j) {
      float v = acc[t][j];
      v = v > 0.f ? v : 0.f;
      h0s[(wave * 16 + q * 4 + j) * HPAD + t * 16 + l16] = (__bf16)v;
    }
  }
  // No barrier: each wave reads only its own 16-row h0s stripe.

  f32x4 acc2[4];
#pragma unroll
  for (int t = 0; t < 4; ++t) acc2[t] = (f32x4){0.f, 0.f, 0.f, 0.f};
#pragma unroll
  for (int kk = 0; kk < HID / 32; ++kk) {
    const bf16x8 aF = *(const bf16x8*)&h0s[(wave * 16 + l16) * HPAD + kk * 32 + q * 8];
#pragma unroll
    for (int t = 0; t < 4; ++t) {
      const bf16x8 bF = *(const bf16x8*)&W1T[(t * 16 + l16) * HID + kk * 32 + q * 8];
      acc2[t] = __builtin_amdgcn_mfma_f32_16x16x32_bf16(aF, bF, acc2[t], 0, 0, 0);
    }
  }

#pragma unroll
  for (int t = 0; t < 4; ++t) {
#pragma unroll
    for (int j = 0; j < 4; ++j) {
      const int grow = rb + wave * 16 + q * 4 + j;
      if (grow < NNODES)
        h1b[(size_t)grow * NCLS + t * 16 + l16] = (__bf16)acc2[t][j];
    }
  }
}

// ---------------------------------------------------------------------------
// Per-bucket CSR fill: degree histogram + padded scan (pad to 8) in LDS,
// rowinfo[w] = {base, pdeg}; writes confined to a 128KB region per block.
// Fixed bucket capacity BCAP removes the inter-bucket scan entirely.
// ---------------------------------------------------------------------------
__global__ __launch_bounds__(256)
void kB3(const int2* __restrict__ bsv, const int* __restrict__ bbase,
         int2* __restrict__ rowinfo, int2* __restrict__ ecsr) {
  __shared__ int dl[NPB];
  __shared__ int cur[NPB];
  __shared__ int s[256];
  const int t = threadIdx.x;
  const int b = blockIdx.x;
  const int nb = b * NPB;
  for (int i = t; i < NPB; i += 256) dl[i] = 0;
  __syncthreads();
  const int beg = bbase[b], end = bbase[b + 1];
  for (int e = beg + t; e < end; e += 256)
    atomicAdd(&dl[((unsigned)bsv[e].x) >> 17], 1);
  __syncthreads();
  const int i0 = t * 2, i1 = t * 2 + 1;
  const int d0 = (i0 < NPB) ? dl[i0] : 0;
  const int d1 = (i1 < NPB) ? dl[i1] : 0;
  const int p0 = (d0 + 7) & ~7, p1 = (d1 + 7) & ~7;
  const int tsum = p0 + p1;
  s[t] = tsum;
  __syncthreads();
  for (int off = 1; off < 256; off <<= 1) {
    int x = (t >= off) ? s[t - off] : 0;
    __syncthreads();
    s[t] += x;
    __syncthreads();
  }
  const int excl = s[t] - tsum;
  const int gb = b * BCAP;
  const int2 z2 = make_int2(0, 0);
  if (i0 < NPB) {
    const int c = gb + excl;
    cur[i0] = c;
    if (nb + i0 < NNODES) rowinfo[nb + i0] = make_int2(c, p0);
    for (int k = d0; k < p0; ++k) ecsr[c + k] = z2;   // zero padding entries
  }
  if (i1 < NPB) {
    const int c = gb + excl + p0;
    cur[i1] = c;
    if (nb + i1 < NNODES) rowinfo[nb + i1] = make_int2(c, p1);
    for (int k = d1; k < p1; ++k) ecsr[c + k] = z2;
  }
  __syncthreads();
  for (int e = beg + t; e < end; e += 256) {
    const int2 sv = bsv[e];
    const int ld = ((unsigned)sv.x) >> 17;
    const int p = atomicAdd(&cur[ld], 1);             // LDS atomic
    ecsr[p] = make_int2(sv.x & 0x1FFFF, sv.y);
  }
}

// ---------------------------------------------------------------------------
// SpMM gather: one wave per dst row, lane = output column. Degree padded
// to 8 -> 8 independent 128B line-gathers in flight per iteration.
// ---------------------------------------------------------------------------
template <typename OUT_T>
__global__ __launch_bounds__(256, 8)
void k_spmm(const int2* __restrict__ rowinfo, const int2* __restrict__ ecsr,
            const __bf16* __restrict__ x, OUT_T* __restrict__ y) {
  const int wl   = (blockIdx.x * 256 + threadIdx.x) >> 6;
  const int w    = __builtin_amdgcn_readfirstlane(wl);   // 25000*4 waves = NNODES
  const int lane = threadIdx.x & 63;
  const int2 ri  = rowinfo[w];                           // {base, pdeg}
  const int base = ri.x, pdeg = ri.y;
  float acc = 0.f;
  for (int j = 0; j < pdeg; j += 8) {
    const int4 m0 = *(const int4*)&ecsr[base + j];
    const int4 m1 = *(const int4*)&ecsr[base + j + 2];
    const int4 m2 = *(const int4*)&ecsr[base + j + 4];
    const int4 m3 = *(const int4*)&ecsr[base + j + 6];
    const float x0 = (float)x[(size_t)m0.x * NCLS + lane];
    const float x1 = (float)x[(size_t)m0.z * NCLS + lane];
    const float x2 = (float)x[(size_t)m1.x * NCLS + lane];
    const float x3 = (float)x[(size_t)m1.z * NCLS + lane];
    const float x4 = (float)x[(size_t)m2.x * NCLS + lane];
    const float x5 = (float)x[(size_t)m2.z * NCLS + lane];
    const float x6 = (float)x[(size_t)m3.x * NCLS + lane];
    const float x7 = (float)x[(size_t)m3.z * NCLS + lane];
    acc += __int_as_float(m0.y) * x0;
    acc += __int_as_float(m0.w) * x1;
    acc += __int_as_float(m1.y) * x2;
    acc += __int_as_float(m1.w) * x3;
    acc += __int_as_float(m2.y) * x4;
    acc += __int_as_float(m2.w) * x5;
    acc += __int_as_float(m3.y) * x6;
    acc += __int_as_float(m3.w) * x7;
  }
  y[(size_t)w * NCLS + lane] = (OUT_T)acc;
}

// ---------------------------------------------------------------------------
extern "C" void kernel_launch(void* const* d_in, const int* in_sizes, int n_in,
                              void* d_out, int out_size, void* d_ws, size_t ws_size,
                              hipStream_t stream) {
  const float* feat = (const float*)d_in[0];
  const float* W0   = (const float*)d_in[1];
  const float* W1   = (const float*)d_in[2];
  const float* eval = (const float*)d_in[3];
  const int*   esrc = (const int*)d_in[4];
  const int*   edst = (const int*)d_in[5];
  float* out = (float*)d_out;

  // Workspace (~60.5 MB). bsv lives in d_out (exactly NEDGES int2 = 25.6 MB,
  // dead after kB3; final spmm overwrites d_out).
  char* p = (char*)d_ws;
  int2*   ecsr    = (int2*)p;   p += (size_t)NBUCK * BCAP * 8;  // 33,554,432
  int2*   rowinfo = (int2*)p;   p += (size_t)NCAP * 8;          // 800,768
  int*    my_base = (int*)p;    p += 400384;
  int*    gcnt    = (int*)p;    p += 1024;
  int*    bbase   = (int*)p;    p += 2048;
  __bf16* W0T     = (__bf16*)p; p += 131072;
  __bf16* W1T     = (__bf16*)p; p += 16384;
  __bf16* h1b     = (__bf16*)p; p += 12800000;
  __bf16* h2b     = (__bf16*)p; p += 12800000;
  int2*   bsv     = (int2*)d_out;                               // 25,600,000

  hipMemsetAsync(gcnt, 0, NBUCK * sizeof(int), stream);
  k_count_wcvt <<<NCHUNKB + 1, 256, 0, stream>>>(edst, gcnt, my_base,
                                                 W0, W1, W0T, W1T);
  kA_bscan     <<<1, 256, 0, stream>>>(gcnt, bbase);
  k_scatter_gemm<<<NCHUNKB + (NNODES + 63) / 64, 256, 0, stream>>>(
      edst, esrc, eval, bbase, my_base, bsv, feat, W0T, W1T, h1b);
  kB3          <<<NBUCK, 256, 0, stream>>>(bsv, bbase, rowinfo, ecsr);

  k_spmm<__bf16><<<NNODES / 4, 256, 0, stream>>>(rowinfo, ecsr, h1b, h2b);
  k_spmm<float> <<<NNODES / 4, 256, 0, stream>>>(rowinfo, ecsr, h2b, out);

  (void)in_sizes; (void)n_in; (void)out_size; (void)ws_size;
}